// Round 20
// baseline (262.990 us; speedup 1.0000x reference)
//
#include <hip/hip_runtime.h>

#define EPSN 1e-12f
#define TILE 2048   // edges per pass-1 tile (782 tiles ~ 3 blocks/CU)
#define BSH 8       // bucket shift: 256 nodes per coarse bucket
#define BNODES 256
#define SBMAX 512   // LDS array cap for bucket counters (nsb=391 fits)
#define BCAP 4608   // fixed slots per bucket (mean 4092, max ~4310 = 8 sigma)

using frag_ab = __attribute__((ext_vector_type(8))) short;   // 8 bf16
using frag_cd = __attribute__((ext_vector_type(4))) float;   // 4 fp32

__device__ inline unsigned short f2bf(float x) {
    union { float f; unsigned u; } v; v.f = x;
    unsigned r = v.u + 0x7fffu + ((v.u >> 16) & 1u);   // round-to-nearest-even
    return (unsigned short)(r >> 16);
}
__device__ inline float bf2f(unsigned short b) {
    union { unsigned u; float f; } v; v.u = ((unsigned)b) << 16; return v.f;
}
__device__ inline void upadd2(uint2 u, float* a) {
    a[0] += bf2f((unsigned short)u.x); a[1] += bf2f((unsigned short)(u.x >> 16));
    a[2] += bf2f((unsigned short)u.y); a[3] += bf2f((unsigned short)(u.y >> 16));
}

// ---------------- fused prep + pass-1a tile histogram -------------------------
// Blocks [0,nt): per-tile histogram over coarse buckets, TILE-MAJOR output
// (contiguous single-writer lines). Blocks [nt,..): pre-linear, weight packs,
// sg zero.
__global__ __launch_bounds__(256) void prep_all(
    const float* __restrict__ x, const float* __restrict__ pw,
    const float* __restrict__ pb, unsigned short* __restrict__ h0, int n,
    const float* __restrict__ w1l, const float* __restrict__ w1r,
    unsigned short* __restrict__ wpk1,
    const float* __restrict__ w2l, const float* __restrict__ w2r,
    unsigned short* __restrict__ wpk2,
    float* __restrict__ sg, int gtot,
    const int* __restrict__ dst, int* __restrict__ thistT, int e,
    int nsb, int nt) {
    __shared__ int lh[SBMAX];
    int tid = threadIdx.x;
    if (blockIdx.x < nt) {                    // ---- thist part ----
        int b = blockIdx.x;
        for (int i = tid; i < nsb; i += 256) lh[i] = 0;
        __syncthreads();
        int base = b * TILE, lim = min(base + TILE, e);
        for (int i = base + tid; i < lim; i += 256) atomicAdd(&lh[dst[i] >> BSH], 1);
        __syncthreads();
        for (int i = tid; i < nsb; i += 256) thistT[(size_t)b * nsb + i] = lh[i];
        return;
    }
    int idx = (blockIdx.x - nt) * 256 + tid;  // ---- prep part ----
    int npre = n * 32;
    if (idx < npre) {
        int node = idx >> 5, j = idx & 31;
        float v = pb[j];
#pragma unroll
        for (int k = 0; k < 5; ++k) v += x[node * 5 + k] * pw[k * 32 + j];
        h0[idx] = f2bf(fmaxf(v, 0.f));
        return;
    }
    int o = idx - npre;
    if (o < 64 * 64) {                        // conv1 pack: kt=64
        int j = o / 64, k = o % 64;
        float v = (k < 32) ? w1l[k * 64 + j] : w1r[(k - 32) * 64 + j];
        wpk1[o] = f2bf(v);
        return;
    }
    o -= 64 * 64;
    if (o < 64 * 128) {                       // conv2 pack: kt=128
        int j = o / 128, k = o % 128;
        float v = (k < 64) ? w2l[k * 64 + j] : w2r[(k - 64) * 64 + j];
        wpk2[o] = f2bf(v);
        return;
    }
    o -= 64 * 128;
    if (o < gtot) sg[o] = 0.f;
}

// ---------------- pass 1b: per-bucket multi-round scan over tiles -------------
__global__ __launch_bounds__(256) void tscan_k(const int* __restrict__ thistT,
                                               int* __restrict__ toffsT,
                                               int* __restrict__ btot,
                                               int nsb, int nt) {
    __shared__ int wsum[8];
    int b = blockIdx.x;
    int tid = threadIdx.x;
    int lane = tid & 63, w = tid >> 6;
    int run = 0;
    for (int base = 0; base < nt; base += 256) {
        int i = base + tid;
        int x = (i < nt) ? thistT[(size_t)i * nsb + b] : 0;
        int inc = x;
#pragma unroll
        for (int o = 1; o < 64; o <<= 1) {
            int t = __shfl_up(inc, o);
            if (lane >= o) inc += t;
        }
        if (lane == 63) wsum[w] = inc;
        __syncthreads();
        if (tid == 0) {
            int s = 0;
#pragma unroll
            for (int k = 0; k < 4; ++k) { int t = wsum[k]; wsum[k] = s; s += t; }
            wsum[4] = s;
        }
        __syncthreads();
        if (i < nt) toffsT[(size_t)b * nt + i] = inc - x + wsum[w] + run;
        run += wsum[4];
        __syncthreads();   // wsum reused next round
    }
    if (tid == 0) btot[b] = run;
}

// ---------------- pass 1c: scatter into fixed-capacity bucket staging ---------
__global__ __launch_bounds__(256) void scat1_k(const int* __restrict__ src,
                                               const int* __restrict__ dst,
                                               const int* __restrict__ toffsT,
                                               int* __restrict__ staged, int e,
                                               int nsb, int nt) {
    __shared__ int cur[SBMAX];
    int tid = threadIdx.x;
    for (int i = tid; i < nsb; i += 256)
        cur[i] = i * BCAP + toffsT[(size_t)i * nt + blockIdx.x];
    __syncthreads();
    int base = blockIdx.x * TILE;
    int lim = min(base + TILE, e);
    for (int i = base + tid; i < lim; i += 256) {
        int d = dst[i];
        int p = atomicAdd(&cur[d >> BSH], 1);
        staged[p] = (src[i] << BSH) | (d & (BNODES - 1));   // src < 2^24, fits
    }
}

// ---------------- pass 2: per-bucket sort -> padded csr + rofs + deg ----------
__global__ __launch_bounds__(256) void scat2_k(const int* __restrict__ btot,
                                               const int* __restrict__ staged,
                                               int* __restrict__ csr,
                                               int* __restrict__ rofs,
                                               int* __restrict__ deg,
                                               int n, int nsb) {
    __shared__ int h[BNODES];
    __shared__ int cur[BNODES];
    __shared__ int wsum[8];
    int b = blockIdx.x;
    int tid = threadIdx.x;
    int lane = tid & 63, w = tid >> 6;
    int nlo = b << BSH;
    int nn = n - nlo; if (nn > BNODES) nn = BNODES;   // live nodes in bucket
    int lo = b * BCAP, hi = lo + btot[b];
    h[tid] = 0;
    __syncthreads();
    for (int i = lo + tid; i < hi; i += 256) atomicAdd(&h[staged[i] & (BNODES - 1)], 1);
    __syncthreads();
    int x = h[tid];
    int inc = x;
#pragma unroll
    for (int o = 1; o < 64; o <<= 1) {
        int t = __shfl_up(inc, o);
        if (lane >= o) inc += t;
    }
    if (lane == 63) wsum[w] = inc;
    __syncthreads();
    if (tid == 0) {
        int s = 0;
#pragma unroll
        for (int k = 0; k < 4; ++k) { int t = wsum[k]; wsum[k] = s; s += t; }
    }
    __syncthreads();
    int excl = inc - x + wsum[w];
    cur[tid] = excl;
    if (tid < nn) {
        rofs[nlo + tid] = lo + excl;
        deg[nlo + tid] = x;
    }
    __syncthreads();   // all cur[] must be written before scatter
    for (int i = lo + tid; i < hi; i += 256) {
        int v = staged[i];
        int p = atomicAdd(&cur[v & (BNODES - 1)], 1);
        csr[lo + p] = v >> BSH;
    }
}

// ---------------- SAGE conv via MFMA, 16 nodes/block --------------------------
// Gather: uint2 (8B = 4 bf16) per lane. RB adapts so a batch always covers 32
// edges (deg~Poisson(16): 96% of nodes finish in ONE csr->row latency
// exposure; round-19's RB=4 gave conv2 only 16-edge batches, so 44% of nodes
// paid two serial exposures). POOL=true (conv2): epilogue reduces relu'd rows
// per graph segment (batch sorted) and atomicAdds into L2-resident sg.
template <int KIN, bool POOL>
__global__ __launch_bounds__(256) void conv_mfma(
    const int* __restrict__ rofs, const int* __restrict__ deg,
    const int* __restrict__ csr,
    const unsigned short* __restrict__ hin, const unsigned short* __restrict__ wpk,
    const float* __restrict__ bl, const int* __restrict__ batch,
    float* __restrict__ sg, unsigned short* __restrict__ hout, int n) {
    constexpr int KT = 2 * KIN;    // concat [agg|self]
    constexpr int ST = KT + 8;     // LDS row stride in ushorts (16B-aligned rows)
    constexpr int KS = KT / 32;    // MFMA k-steps
    constexpr int LPE = KIN / 4;   // lanes per edge row (8B each)
    constexpr int EPW = 64 / LPE;  // edges per wave-load
    constexpr int RB = (EPW >= 8) ? 4 : 8;   // rounds per ILP batch (32 edges)
    __shared__ unsigned short __attribute__((aligned(16))) Ab[16 * ST];
    __shared__ float __attribute__((aligned(16))) Nb[4][16];
    __shared__ int ro[16];
    __shared__ int dg[16];
    __shared__ int sb[16];

    int tid = threadIdx.x;
    int w = tid >> 6;              // wave id == j-tile
    int lane = tid & 63;
    int quad = lane >> 4;
    int l16 = lane & 15;
    int base = blockIdx.x * 16;
    int ncol = w * 16 + l16;

    if (tid < 16) {
        int nd = base + tid;
        bool v = nd < n;
        ro[tid] = v ? rofs[nd] : 0;
        dg[tid] = v ? deg[nd] : 0;
        if (POOL) sb[tid] = v ? batch[nd] : -1;
    }

    // B fragments: one 16B load each from packed weights
    frag_ab bfrag[KS];
#pragma unroll
    for (int s = 0; s < KS; ++s)
        bfrag[s] = *(const frag_ab*)&wpk[(((ncol * KS) + s) * 4 + quad) * 8];
    float bias = bl[ncol];
    __syncthreads();

    // ---- gather phase: wave w fills LDS rows w*4 .. w*4+3 ----
    int grp = lane / LPE;          // edge slot within a wave-load
    int p = lane % LPE;            // 8B chunk within a row
    for (int i = 0; i < 4; ++i) {
        int li = w * 4 + i;
        int node = base + li;
        if (node >= n) break;
        int beg = ro[li];
        int cnt = dg[li];
        uint2 selfv = make_uint2(0u, 0u);
        if (grp == 1)
            selfv = *(const uint2*)&hin[(size_t)node * KIN + p * 4];
        float a[4] = {0.f, 0.f, 0.f, 0.f};
        for (int e0 = 0; e0 < cnt; e0 += RB * EPW) {
            int idx[RB];
            uint2 u[RB];
#pragma unroll
            for (int r = 0; r < RB; ++r) {
                int ee = e0 + r * EPW + grp;
                int cl = (ee < cnt) ? ee : (cnt - 1);   // clamp (cnt>=1 here)
                idx[r] = csr[beg + cl];
            }
#pragma unroll
            for (int r = 0; r < RB; ++r)
                u[r] = *(const uint2*)&hin[(size_t)idx[r] * KIN + p * 4];
#pragma unroll
            for (int r = 0; r < RB; ++r)
                if (e0 + r * EPW + grp < cnt) upadd2(u[r], a);
        }
#pragma unroll
        for (int o = LPE; o < 64; o <<= 1) {
#pragma unroll
            for (int q = 0; q < 4; ++q) a[q] += __shfl_xor(a[q], o);
        }
        float inv = (cnt > 0) ? 1.0f / (float)cnt : 0.0f;
        if (grp == 0) {
            uint2 o2;
            o2.x = (unsigned)f2bf(a[0] * inv) | ((unsigned)f2bf(a[1] * inv) << 16);
            o2.y = (unsigned)f2bf(a[2] * inv) | ((unsigned)f2bf(a[3] * inv) << 16);
            *(uint2*)&Ab[li * ST + p * 4] = o2;
        } else if (grp == 1) {
            *(uint2*)&Ab[li * ST + KIN + p * 4] = selfv;
        }
    }
    __syncthreads();

    // ---- MFMA phase: wave w computes cols [w*16, w*16+16) for the M-tile ----
    frag_cd acc = (frag_cd){0.f, 0.f, 0.f, 0.f};
#pragma unroll
    for (int s = 0; s < KS; ++s) {
        frag_ab af = *(frag_ab*)&Ab[l16 * ST + s * 32 + quad * 8];
        acc = __builtin_amdgcn_mfma_f32_16x16x32_bf16(af, bfrag[s], acc, 0, 0, 0);
    }

    // ---- epilogue: bias, per-node L2 norm (cross-wave via LDS), relu ----
    float vv[4], q[4];
#pragma unroll
    for (int i = 0; i < 4; ++i) {
        float v = acc[i] + bias;   // D row = quad*4+i (node), col = l16
        vv[i] = v;
        q[i] = v * v;
    }
#pragma unroll
    for (int o = 1; o < 16; o <<= 1) {
#pragma unroll
        for (int i = 0; i < 4; ++i) q[i] += __shfl_xor(q[i], o);
    }
    if (l16 == 0)
        *(float4*)&Nb[w][quad * 4] = make_float4(q[0], q[1], q[2], q[3]);
    __syncthreads();

    float s0 = 0.f, s1 = 0.f, s2 = 0.f, s3 = 0.f;
#pragma unroll
    for (int ww = 0; ww < 4; ++ww) {
        float4 xq = *(const float4*)&Nb[ww][quad * 4];
        s0 += xq.x; s1 += xq.y; s2 += xq.z; s3 += xq.w;
    }
    float ss[4] = {s0, s1, s2, s3};
    float pv[4];
#pragma unroll
    for (int i = 0; i < 4; ++i) {
        float nv = fmaxf(sqrtf(ss[i]), EPSN);
        pv[i] = fmaxf(vv[i] / nv, 0.f);
    }

    if (!POOL) {
#pragma unroll
        for (int i = 0; i < 4; ++i) {
            int node = base + quad * 4 + i;
            if (node < n)
                hout[(size_t)node * 64 + ncol] = f2bf(pv[i]);
        }
    } else {
        // per-graph-segment sums; batch sorted -> g in [g0,g1], small span
        int g0 = sb[0];
        int g1 = sb[min(15, n - 1 - base)];
        for (int g = g0; g <= g1; ++g) {
            float s = 0.f;
#pragma unroll
            for (int i = 0; i < 4; ++i)
                if (sb[quad * 4 + i] == g) s += pv[i];
            s += __shfl_xor(s, 16);
            s += __shfl_xor(s, 32);
            if (quad == 0) atomicAdd(&sg[(size_t)g * 64 + ncol], s);
        }
    }
}

// ---------------- head MLP per graph (counts via binary search) ---------------
__global__ __launch_bounds__(64) void mlp_k(
    const float* __restrict__ sg, const int* __restrict__ batch, int n,
    const float* __restrict__ p1w, const float* __restrict__ p1b,
    const float* __restrict__ p2w, const float* __restrict__ p2b,
    const float* __restrict__ ow, const float* __restrict__ ob,
    float* __restrict__ out) {
    __shared__ float gmean[64];
    __shared__ float a1[64];
    __shared__ float a2[16];
    int g = blockIdx.x;
    int j = threadIdx.x;
    int lo = 0, hi = n;
    while (lo < hi) { int m = (lo + hi) >> 1; if (batch[m] < g) lo = m + 1; else hi = m; }
    int start = lo;
    hi = n;
    while (lo < hi) { int m = (lo + hi) >> 1; if (batch[m] < g + 1) lo = m + 1; else hi = m; }
    float c = (float)(lo - start);
    gmean[j] = sg[(size_t)g * 64 + j] / fmaxf(c, 1.0f);
    __syncthreads();
    float v = p1b[j];
#pragma unroll 8
    for (int k = 0; k < 64; ++k) v = fmaf(gmean[k], p1w[k * 64 + j], v);
    a1[j] = fmaxf(v, 0.f);
    __syncthreads();
    if (j < 16) {
        float v2 = p2b[j];
#pragma unroll 8
        for (int k = 0; k < 64; ++k) v2 = fmaf(a1[k], p2w[k * 16 + j], v2);
        a2[j] = fmaxf(v2, 0.f);
    }
    __syncthreads();
    if (j == 0) {
        float v3 = ob[0];
#pragma unroll
        for (int k = 0; k < 16; ++k) v3 = fmaf(a2[k], ow[k], v3);
        out[g] = v3;
    }
}

extern "C" void kernel_launch(void* const* d_in, const int* in_sizes, int n_in,
                              void* d_out, int out_size, void* d_ws, size_t ws_size,
                              hipStream_t stream) {
    const float* x     = (const float*)d_in[0];
    const int*   ei    = (const int*)d_in[1];
    const int*   batch = (const int*)d_in[2];
    const float* pre_w = (const float*)d_in[4];
    const float* pre_b = (const float*)d_in[5];
    const float* c1_wl = (const float*)d_in[6];
    const float* c1_bl = (const float*)d_in[7];
    const float* c1_wr = (const float*)d_in[8];
    const float* c2_wl = (const float*)d_in[9];
    const float* c2_bl = (const float*)d_in[10];
    const float* c2_wr = (const float*)d_in[11];
    const float* p1w   = (const float*)d_in[12];
    const float* p1b   = (const float*)d_in[13];
    const float* p2w   = (const float*)d_in[14];
    const float* p2b   = (const float*)d_in[15];
    const float* ow    = (const float*)d_in[16];
    const float* ob    = (const float*)d_in[17];

    const int N = in_sizes[0] / 5;
    const int E = in_sizes[1] / 2;
    const int G = out_size;
    const int NT = (E + TILE - 1) / TILE;        // pass-1 tiles (782)
    const int NSB = (N + BNODES - 1) / BNODES;   // coarse buckets (391)
    const int* src = ei;
    const int* dst = ei + E;

    // workspace layout
    unsigned short* h0u = (unsigned short*)d_ws;                    // N*32 bf16
    unsigned short* h1u = h0u + (size_t)N * 32;                     // N*64 bf16
    unsigned short* wpk1 = h1u + (size_t)N * 64;                    // 64*64
    unsigned short* wpk2 = wpk1 + 64 * 64;                          // 64*128
    float* sg    = (float*)(wpk2 + 64 * 128);                       // G*64
    int* rofs    = (int*)(sg + (size_t)G * 64);                     // N
    int* deg     = rofs + N;                                        // N
    int* btot    = deg + N;                                         // NSB
    int* thistT  = btot + NSB;                                      // NT*NSB (tile-major)
    int* toffsT  = thistT + (size_t)NT * NSB;                       // NSB*NT (bucket-major)
    int* staged  = toffsT + (size_t)NSB * NT;                       // NSB*BCAP
    int* csr     = staged + (size_t)NSB * BCAP;                     // NSB*BCAP

    int prep_tot = N * 32 + 64 * 64 + 64 * 128 + G * 64;
    int prep_blocks = (prep_tot + 255) / 256;
    prep_all<<<NT + prep_blocks, 256, 0, stream>>>(
        x, pre_w, pre_b, h0u, N, c1_wl, c1_wr, wpk1, c2_wl, c2_wr, wpk2,
        sg, G * 64, dst, thistT, E, NSB, NT);

    tscan_k<<<NSB, 256, 0, stream>>>(thistT, toffsT, btot, NSB, NT);
    scat1_k<<<NT, 256, 0, stream>>>(src, dst, toffsT, staged, E, NSB, NT);
    scat2_k<<<NSB, 256, 0, stream>>>(btot, staged, csr, rofs, deg, N, NSB);

    conv_mfma<32, false><<<(N + 15) / 16, 256, 0, stream>>>(
        rofs, deg, csr, h0u, wpk1, c1_bl, batch, sg, h1u, N);
    conv_mfma<64, true><<<(N + 15) / 16, 256, 0, stream>>>(
        rofs, deg, csr, h1u, wpk2, c2_bl, batch, sg, nullptr, N);

    mlp_k<<<G, 64, 0, stream>>>(sg, batch, N, p1w, p1b, p2w, p2b, ow, ob,
                                (float*)d_out);
}

// Round 21
// 250.539 us; speedup vs baseline: 1.0497x; 1.0497x over previous
//
#include <hip/hip_runtime.h>

#define EPSN 1e-12f
#define TILE 2048   // edges per pass-1 tile (782 tiles ~ 3 blocks/CU)
#define BSH 8       // bucket shift: 256 nodes per coarse bucket
#define BNODES 256
#define SBMAX 512   // LDS array cap for bucket counters (nsb=391 fits)
#define BCAP 4608   // fixed slots per bucket (mean 4092, max ~4310 = 8 sigma)

using frag_ab = __attribute__((ext_vector_type(8))) short;   // 8 bf16
using frag_cd = __attribute__((ext_vector_type(4))) float;   // 4 fp32

__device__ inline unsigned short f2bf(float x) {
    union { float f; unsigned u; } v; v.f = x;
    unsigned r = v.u + 0x7fffu + ((v.u >> 16) & 1u);   // round-to-nearest-even
    return (unsigned short)(r >> 16);
}
__device__ inline float bf2f(unsigned short b) {
    union { unsigned u; float f; } v; v.u = ((unsigned)b) << 16; return v.f;
}
__device__ inline void upadd2(uint2 u, float* a) {
    a[0] += bf2f((unsigned short)u.x); a[1] += bf2f((unsigned short)(u.x >> 16));
    a[2] += bf2f((unsigned short)u.y); a[3] += bf2f((unsigned short)(u.y >> 16));
}

// ---------------- fused prep + pass-1a tile histogram -------------------------
// Blocks [0,nt): per-tile histogram over coarse buckets, TILE-MAJOR output
// (contiguous single-writer lines). Blocks [nt,..): pre-linear, weight packs,
// sg zero.
__global__ __launch_bounds__(256) void prep_all(
    const float* __restrict__ x, const float* __restrict__ pw,
    const float* __restrict__ pb, unsigned short* __restrict__ h0, int n,
    const float* __restrict__ w1l, const float* __restrict__ w1r,
    unsigned short* __restrict__ wpk1,
    const float* __restrict__ w2l, const float* __restrict__ w2r,
    unsigned short* __restrict__ wpk2,
    float* __restrict__ sg, int gtot,
    const int* __restrict__ dst, int* __restrict__ thistT, int e,
    int nsb, int nt) {
    __shared__ int lh[SBMAX];
    int tid = threadIdx.x;
    if (blockIdx.x < nt) {                    // ---- thist part ----
        int b = blockIdx.x;
        for (int i = tid; i < nsb; i += 256) lh[i] = 0;
        __syncthreads();
        int base = b * TILE, lim = min(base + TILE, e);
        for (int i = base + tid; i < lim; i += 256) atomicAdd(&lh[dst[i] >> BSH], 1);
        __syncthreads();
        for (int i = tid; i < nsb; i += 256) thistT[(size_t)b * nsb + i] = lh[i];
        return;
    }
    int idx = (blockIdx.x - nt) * 256 + tid;  // ---- prep part ----
    int npre = n * 32;
    if (idx < npre) {
        int node = idx >> 5, j = idx & 31;
        float v = pb[j];
#pragma unroll
        for (int k = 0; k < 5; ++k) v += x[node * 5 + k] * pw[k * 32 + j];
        h0[idx] = f2bf(fmaxf(v, 0.f));
        return;
    }
    int o = idx - npre;
    if (o < 64 * 64) {                        // conv1 pack: kt=64
        int j = o / 64, k = o % 64;
        float v = (k < 32) ? w1l[k * 64 + j] : w1r[(k - 32) * 64 + j];
        wpk1[o] = f2bf(v);
        return;
    }
    o -= 64 * 64;
    if (o < 64 * 128) {                       // conv2 pack: kt=128
        int j = o / 128, k = o % 128;
        float v = (k < 64) ? w2l[k * 64 + j] : w2r[(k - 64) * 64 + j];
        wpk2[o] = f2bf(v);
        return;
    }
    o -= 64 * 128;
    if (o < gtot) sg[o] = 0.f;
}

// ---------------- pass 1b: per-bucket multi-round scan over tiles -------------
__global__ __launch_bounds__(256) void tscan_k(const int* __restrict__ thistT,
                                               int* __restrict__ toffsT,
                                               int* __restrict__ btot,
                                               int nsb, int nt) {
    __shared__ int wsum[8];
    int b = blockIdx.x;
    int tid = threadIdx.x;
    int lane = tid & 63, w = tid >> 6;
    int run = 0;
    for (int base = 0; base < nt; base += 256) {
        int i = base + tid;
        int x = (i < nt) ? thistT[(size_t)i * nsb + b] : 0;
        int inc = x;
#pragma unroll
        for (int o = 1; o < 64; o <<= 1) {
            int t = __shfl_up(inc, o);
            if (lane >= o) inc += t;
        }
        if (lane == 63) wsum[w] = inc;
        __syncthreads();
        if (tid == 0) {
            int s = 0;
#pragma unroll
            for (int k = 0; k < 4; ++k) { int t = wsum[k]; wsum[k] = s; s += t; }
            wsum[4] = s;
        }
        __syncthreads();
        if (i < nt) toffsT[(size_t)b * nt + i] = inc - x + wsum[w] + run;
        run += wsum[4];
        __syncthreads();   // wsum reused next round
    }
    if (tid == 0) btot[b] = run;
}

// ---------------- pass 1c: scatter into fixed-capacity bucket staging ---------
__global__ __launch_bounds__(256) void scat1_k(const int* __restrict__ src,
                                               const int* __restrict__ dst,
                                               const int* __restrict__ toffsT,
                                               int* __restrict__ staged, int e,
                                               int nsb, int nt) {
    __shared__ int cur[SBMAX];
    int tid = threadIdx.x;
    for (int i = tid; i < nsb; i += 256)
        cur[i] = i * BCAP + toffsT[(size_t)i * nt + blockIdx.x];
    __syncthreads();
    int base = blockIdx.x * TILE;
    int lim = min(base + TILE, e);
    for (int i = base + tid; i < lim; i += 256) {
        int d = dst[i];
        int p = atomicAdd(&cur[d >> BSH], 1);
        staged[p] = (src[i] << BSH) | (d & (BNODES - 1));   // src < 2^24, fits
    }
}

// ---------------- pass 2: per-bucket sort -> padded csr + rofs + deg ----------
__global__ __launch_bounds__(256) void scat2_k(const int* __restrict__ btot,
                                               const int* __restrict__ staged,
                                               int* __restrict__ csr,
                                               int* __restrict__ rofs,
                                               int* __restrict__ deg,
                                               int n, int nsb) {
    __shared__ int h[BNODES];
    __shared__ int cur[BNODES];
    __shared__ int wsum[8];
    int b = blockIdx.x;
    int tid = threadIdx.x;
    int lane = tid & 63, w = tid >> 6;
    int nlo = b << BSH;
    int nn = n - nlo; if (nn > BNODES) nn = BNODES;   // live nodes in bucket
    int lo = b * BCAP, hi = lo + btot[b];
    h[tid] = 0;
    __syncthreads();
    for (int i = lo + tid; i < hi; i += 256) atomicAdd(&h[staged[i] & (BNODES - 1)], 1);
    __syncthreads();
    int x = h[tid];
    int inc = x;
#pragma unroll
    for (int o = 1; o < 64; o <<= 1) {
        int t = __shfl_up(inc, o);
        if (lane >= o) inc += t;
    }
    if (lane == 63) wsum[w] = inc;
    __syncthreads();
    if (tid == 0) {
        int s = 0;
#pragma unroll
        for (int k = 0; k < 4; ++k) { int t = wsum[k]; wsum[k] = s; s += t; }
    }
    __syncthreads();
    int excl = inc - x + wsum[w];
    cur[tid] = excl;
    if (tid < nn) {
        rofs[nlo + tid] = lo + excl;
        deg[nlo + tid] = x;
    }
    __syncthreads();   // all cur[] must be written before scatter
    for (int i = lo + tid; i < hi; i += 256) {
        int v = staged[i];
        int p = atomicAdd(&cur[v & (BNODES - 1)], 1);
        csr[lo + p] = v >> BSH;
    }
}

// ---------------- SAGE conv via MFMA, 16 nodes/block (round-19 version) -------
// Gather: uint2 (8B = 4 bf16) per lane, RB=4 ILP-batched rounds (r20 showed
// RB=8 wastes ~half the issued gather loads when batch > mean degree and
// costs occupancy: clamped-speculative batches must not exceed mean deg).
// POOL=true (conv2): epilogue reduces relu'd rows per graph segment (batch
// sorted) and atomicAdds into L2-resident sg.
template <int KIN, bool POOL>
__global__ __launch_bounds__(256) void conv_mfma(
    const int* __restrict__ rofs, const int* __restrict__ deg,
    const int* __restrict__ csr,
    const unsigned short* __restrict__ hin, const unsigned short* __restrict__ wpk,
    const float* __restrict__ bl, const int* __restrict__ batch,
    float* __restrict__ sg, unsigned short* __restrict__ hout, int n) {
    constexpr int KT = 2 * KIN;    // concat [agg|self]
    constexpr int ST = KT + 8;     // LDS row stride in ushorts (16B-aligned rows)
    constexpr int KS = KT / 32;    // MFMA k-steps
    constexpr int LPE = KIN / 4;   // lanes per edge row (8B each)
    constexpr int EPW = 64 / LPE;  // edges per wave-load
    constexpr int RB = 4;          // rounds per ILP batch
    __shared__ unsigned short __attribute__((aligned(16))) Ab[16 * ST];
    __shared__ float __attribute__((aligned(16))) Nb[4][16];
    __shared__ int ro[16];
    __shared__ int dg[16];
    __shared__ int sb[16];

    int tid = threadIdx.x;
    int w = tid >> 6;              // wave id == j-tile
    int lane = tid & 63;
    int quad = lane >> 4;
    int l16 = lane & 15;
    int base = blockIdx.x * 16;
    int ncol = w * 16 + l16;

    if (tid < 16) {
        int nd = base + tid;
        bool v = nd < n;
        ro[tid] = v ? rofs[nd] : 0;
        dg[tid] = v ? deg[nd] : 0;
        if (POOL) sb[tid] = v ? batch[nd] : -1;
    }

    // B fragments: one 16B load each from packed weights
    frag_ab bfrag[KS];
#pragma unroll
    for (int s = 0; s < KS; ++s)
        bfrag[s] = *(const frag_ab*)&wpk[(((ncol * KS) + s) * 4 + quad) * 8];
    float bias = bl[ncol];
    __syncthreads();

    // ---- gather phase: wave w fills LDS rows w*4 .. w*4+3 ----
    int grp = lane / LPE;          // edge slot within a wave-load
    int p = lane % LPE;            // 8B chunk within a row
    for (int i = 0; i < 4; ++i) {
        int li = w * 4 + i;
        int node = base + li;
        if (node >= n) break;
        int beg = ro[li];
        int cnt = dg[li];
        uint2 selfv = make_uint2(0u, 0u);
        if (grp == 1)
            selfv = *(const uint2*)&hin[(size_t)node * KIN + p * 4];
        float a[4] = {0.f, 0.f, 0.f, 0.f};
        for (int e0 = 0; e0 < cnt; e0 += RB * EPW) {
            int idx[RB];
            uint2 u[RB];
#pragma unroll
            for (int r = 0; r < RB; ++r) {
                int ee = e0 + r * EPW + grp;
                int cl = (ee < cnt) ? ee : (cnt - 1);   // clamp (cnt>=1 here)
                idx[r] = csr[beg + cl];
            }
#pragma unroll
            for (int r = 0; r < RB; ++r)
                u[r] = *(const uint2*)&hin[(size_t)idx[r] * KIN + p * 4];
#pragma unroll
            for (int r = 0; r < RB; ++r)
                if (e0 + r * EPW + grp < cnt) upadd2(u[r], a);
        }
#pragma unroll
        for (int o = LPE; o < 64; o <<= 1) {
#pragma unroll
            for (int q = 0; q < 4; ++q) a[q] += __shfl_xor(a[q], o);
        }
        float inv = (cnt > 0) ? 1.0f / (float)cnt : 0.0f;
        if (grp == 0) {
            uint2 o2;
            o2.x = (unsigned)f2bf(a[0] * inv) | ((unsigned)f2bf(a[1] * inv) << 16);
            o2.y = (unsigned)f2bf(a[2] * inv) | ((unsigned)f2bf(a[3] * inv) << 16);
            *(uint2*)&Ab[li * ST + p * 4] = o2;
        } else if (grp == 1) {
            *(uint2*)&Ab[li * ST + KIN + p * 4] = selfv;
        }
    }
    __syncthreads();

    // ---- MFMA phase: wave w computes cols [w*16, w*16+16) for the M-tile ----
    frag_cd acc = (frag_cd){0.f, 0.f, 0.f, 0.f};
#pragma unroll
    for (int s = 0; s < KS; ++s) {
        frag_ab af = *(frag_ab*)&Ab[l16 * ST + s * 32 + quad * 8];
        acc = __builtin_amdgcn_mfma_f32_16x16x32_bf16(af, bfrag[s], acc, 0, 0, 0);
    }

    // ---- epilogue: bias, per-node L2 norm (cross-wave via LDS), relu ----
    float vv[4], q[4];
#pragma unroll
    for (int i = 0; i < 4; ++i) {
        float v = acc[i] + bias;   // D row = quad*4+i (node), col = l16
        vv[i] = v;
        q[i] = v * v;
    }
#pragma unroll
    for (int o = 1; o < 16; o <<= 1) {
#pragma unroll
        for (int i = 0; i < 4; ++i) q[i] += __shfl_xor(q[i], o);
    }
    if (l16 == 0)
        *(float4*)&Nb[w][quad * 4] = make_float4(q[0], q[1], q[2], q[3]);
    __syncthreads();

    float s0 = 0.f, s1 = 0.f, s2 = 0.f, s3 = 0.f;
#pragma unroll
    for (int ww = 0; ww < 4; ++ww) {
        float4 xq = *(const float4*)&Nb[ww][quad * 4];
        s0 += xq.x; s1 += xq.y; s2 += xq.z; s3 += xq.w;
    }
    float ss[4] = {s0, s1, s2, s3};
    float pv[4];
#pragma unroll
    for (int i = 0; i < 4; ++i) {
        float nv = fmaxf(sqrtf(ss[i]), EPSN);
        pv[i] = fmaxf(vv[i] / nv, 0.f);
    }

    if (!POOL) {
#pragma unroll
        for (int i = 0; i < 4; ++i) {
            int node = base + quad * 4 + i;
            if (node < n)
                hout[(size_t)node * 64 + ncol] = f2bf(pv[i]);
        }
    } else {
        // per-graph-segment sums; batch sorted -> g in [g0,g1], small span
        int g0 = sb[0];
        int g1 = sb[min(15, n - 1 - base)];
        for (int g = g0; g <= g1; ++g) {
            float s = 0.f;
#pragma unroll
            for (int i = 0; i < 4; ++i)
                if (sb[quad * 4 + i] == g) s += pv[i];
            s += __shfl_xor(s, 16);
            s += __shfl_xor(s, 32);
            if (quad == 0) atomicAdd(&sg[(size_t)g * 64 + ncol], s);
        }
    }
}

// ---------------- head MLP per graph (counts via binary search) ---------------
__global__ __launch_bounds__(64) void mlp_k(
    const float* __restrict__ sg, const int* __restrict__ batch, int n,
    const float* __restrict__ p1w, const float* __restrict__ p1b,
    const float* __restrict__ p2w, const float* __restrict__ p2b,
    const float* __restrict__ ow, const float* __restrict__ ob,
    float* __restrict__ out) {
    __shared__ float gmean[64];
    __shared__ float a1[64];
    __shared__ float a2[16];
    int g = blockIdx.x;
    int j = threadIdx.x;
    int lo = 0, hi = n;
    while (lo < hi) { int m = (lo + hi) >> 1; if (batch[m] < g) lo = m + 1; else hi = m; }
    int start = lo;
    hi = n;
    while (lo < hi) { int m = (lo + hi) >> 1; if (batch[m] < g + 1) lo = m + 1; else hi = m; }
    float c = (float)(lo - start);
    gmean[j] = sg[(size_t)g * 64 + j] / fmaxf(c, 1.0f);
    __syncthreads();
    float v = p1b[j];
#pragma unroll 8
    for (int k = 0; k < 64; ++k) v = fmaf(gmean[k], p1w[k * 64 + j], v);
    a1[j] = fmaxf(v, 0.f);
    __syncthreads();
    if (j < 16) {
        float v2 = p2b[j];
#pragma unroll 8
        for (int k = 0; k < 64; ++k) v2 = fmaf(a1[k], p2w[k * 16 + j], v2);
        a2[j] = fmaxf(v2, 0.f);
    }
    __syncthreads();
    if (j == 0) {
        float v3 = ob[0];
#pragma unroll
        for (int k = 0; k < 16; ++k) v3 = fmaf(a2[k], ow[k], v3);
        out[g] = v3;
    }
}

extern "C" void kernel_launch(void* const* d_in, const int* in_sizes, int n_in,
                              void* d_out, int out_size, void* d_ws, size_t ws_size,
                              hipStream_t stream) {
    const float* x     = (const float*)d_in[0];
    const int*   ei    = (const int*)d_in[1];
    const int*   batch = (const int*)d_in[2];
    const float* pre_w = (const float*)d_in[4];
    const float* pre_b = (const float*)d_in[5];
    const float* c1_wl = (const float*)d_in[6];
    const float* c1_bl = (const float*)d_in[7];
    const float* c1_wr = (const float*)d_in[8];
    const float* c2_wl = (const float*)d_in[9];
    const float* c2_bl = (const float*)d_in[10];
    const float* c2_wr = (const float*)d_in[11];
    const float* p1w   = (const float*)d_in[12];
    const float* p1b   = (const float*)d_in[13];
    const float* p2w   = (const float*)d_in[14];
    const float* p2b   = (const float*)d_in[15];
    const float* ow    = (const float*)d_in[16];
    const float* ob    = (const float*)d_in[17];

    const int N = in_sizes[0] / 5;
    const int E = in_sizes[1] / 2;
    const int G = out_size;
    const int NT = (E + TILE - 1) / TILE;        // pass-1 tiles (782)
    const int NSB = (N + BNODES - 1) / BNODES;   // coarse buckets (391)
    const int* src = ei;
    const int* dst = ei + E;

    // workspace layout
    unsigned short* h0u = (unsigned short*)d_ws;                    // N*32 bf16
    unsigned short* h1u = h0u + (size_t)N * 32;                     // N*64 bf16
    unsigned short* wpk1 = h1u + (size_t)N * 64;                    // 64*64
    unsigned short* wpk2 = wpk1 + 64 * 64;                          // 64*128
    float* sg    = (float*)(wpk2 + 64 * 128);                       // G*64
    int* rofs    = (int*)(sg + (size_t)G * 64);                     // N
    int* deg     = rofs + N;                                        // N
    int* btot    = deg + N;                                         // NSB
    int* thistT  = btot + NSB;                                      // NT*NSB (tile-major)
    int* toffsT  = thistT + (size_t)NT * NSB;                       // NSB*NT (bucket-major)
    int* staged  = toffsT + (size_t)NSB * NT;                       // NSB*BCAP
    int* csr     = staged + (size_t)NSB * BCAP;                     // NSB*BCAP

    int prep_tot = N * 32 + 64 * 64 + 64 * 128 + G * 64;
    int prep_blocks = (prep_tot + 255) / 256;
    prep_all<<<NT + prep_blocks, 256, 0, stream>>>(
        x, pre_w, pre_b, h0u, N, c1_wl, c1_wr, wpk1, c2_wl, c2_wr, wpk2,
        sg, G * 64, dst, thistT, E, NSB, NT);

    tscan_k<<<NSB, 256, 0, stream>>>(thistT, toffsT, btot, NSB, NT);
    scat1_k<<<NT, 256, 0, stream>>>(src, dst, toffsT, staged, E, NSB, NT);
    scat2_k<<<NSB, 256, 0, stream>>>(btot, staged, csr, rofs, deg, N, NSB);

    conv_mfma<32, false><<<(N + 15) / 16, 256, 0, stream>>>(
        rofs, deg, csr, h0u, wpk1, c1_bl, batch, sg, h1u, N);
    conv_mfma<64, true><<<(N + 15) / 16, 256, 0, stream>>>(
        rofs, deg, csr, h1u, wpk2, c2_bl, batch, sg, nullptr, N);

    mlp_k<<<G, 64, 0, stream>>>(sg, batch, N, p1w, p1b, p2w, p2b, ow, ob,
                                (float*)d_out);
}